// Round 1
// baseline (1396.312 us; speedup 1.0000x reference)
//
#include <hip/hip_runtime.h>
#include <math.h>

#define N_NODES 100000
#define N_EDGES 1600000
#define EP (N_EDGES + N_NODES)   // edges + self loops = 1,700,000
#define F 64

// ---- order-preserving float <-> uint encoding for atomicMax on floats ----
__device__ __forceinline__ unsigned enc_f32(float f) {
    unsigned u = __float_as_uint(f);
    return (u & 0x80000000u) ? ~u : (u | 0x80000000u);
}
__device__ __forceinline__ float dec_f32(unsigned u) {
    return (u & 0x80000000u) ? __uint_as_float(u & 0x7FFFFFFFu)
                             : __uint_as_float(~u);
}

// ---- K1: h = X @ W ; asrc = h . aw_s ; adst = h . aw_d ----
// one thread per output element; a wave (64 lanes) holds one full row of h
__global__ __launch_bounds__(256) void k_gemm(
    const float* __restrict__ X, const float* __restrict__ W,
    const float* __restrict__ aw_s, const float* __restrict__ aw_d,
    float* __restrict__ H, float* __restrict__ asrc, float* __restrict__ adst)
{
    int gid = blockIdx.x * 256 + threadIdx.x;
    int r = gid >> 6;
    int c = gid & 63;
    if (r >= N_NODES) return;
    const float* xr = X + r * F;
    float acc = 0.f;
#pragma unroll
    for (int k = 0; k < F; ++k) acc = fmaf(xr[k], W[k * F + c], acc);
    H[r * F + c] = acc;
    // wave reduction for the two attention dot products
    float va = acc * aw_s[c];
    float vd = acc * aw_d[c];
#pragma unroll
    for (int off = 32; off; off >>= 1) {
        va += __shfl_xor(va, off, 64);
        vd += __shfl_xor(vd, off, 64);
    }
    if (c == 0) { asrc[r] = va; adst[r] = vd; }
}

// ---- K2: edge scores + segment max (atomicMax on encoded floats) ----
__global__ __launch_bounds__(256) void k_edge_score(
    const int* __restrict__ esrc, const int* __restrict__ edst,
    const float* __restrict__ asrc, const float* __restrict__ adst,
    float* __restrict__ score, unsigned* __restrict__ m)
{
    int e = blockIdx.x * 256 + threadIdx.x;
    if (e >= EP) return;
    int s_, d_;
    if (e < N_EDGES) { s_ = esrc[e]; d_ = edst[e]; }
    else             { s_ = d_ = e - N_EDGES; }   // self loop
    float sc = asrc[s_] + adst[d_];
    sc = (sc >= 0.f) ? sc : 0.2f * sc;            // LeakyReLU(0.2)
    score[e] = sc;
    atomicMax(m + d_, enc_f32(sc));
}

// ---- K3: w = exp(score - m[dst]); s[dst]+=w; acc[dst,:] += w*H[src,:] ----
// one wave per edge, lane = feature -> coalesced 256B gather + 256B atomics
__global__ __launch_bounds__(256) void k_edge_aggr(
    const int* __restrict__ esrc, const int* __restrict__ edst,
    const float* __restrict__ score, const unsigned* __restrict__ m,
    const float* __restrict__ H, float* __restrict__ s, float* __restrict__ acc)
{
    int wave = (blockIdx.x * 256 + threadIdx.x) >> 6;
    int lane = threadIdx.x & 63;
    if (wave >= EP) return;
    int s_, d_;
    if (wave < N_EDGES) { s_ = esrc[wave]; d_ = edst[wave]; }
    else                { s_ = d_ = wave - N_EDGES; }
    float w = expf(score[wave] - dec_f32(m[d_]));
    if (lane == 0) atomicAdd(s + d_, w);
    atomicAdd(acc + d_ * F + lane, w * H[s_ * F + lane]);
}

// ---- K4a: layer-1 finalize: /s, +bias, relu, BatchNorm(eval) ----
__global__ __launch_bounds__(256) void k_finalize1(
    const float* __restrict__ acc, const float* __restrict__ s,
    const float* __restrict__ b,
    const float* __restrict__ gamma, const float* __restrict__ beta,
    const float* __restrict__ mean,  const float* __restrict__ var,
    float* __restrict__ out)
{
    int gid = blockIdx.x * 256 + threadIdx.x;
    if (gid >= N_NODES * F) return;
    int r = gid >> 6, c = gid & 63;
    float o = acc[gid] / (s[r] + 1e-16f) + b[c];
    o = fmaxf(o, 0.f);
    o = (o - mean[c]) * (1.0f / sqrtf(var[c] + 1e-5f)) * gamma[c] + beta[c];
    out[gid] = o;
}

// ---- K4b: layer-2 finalize: /s, +bias, relu ----
__global__ __launch_bounds__(256) void k_finalize2(
    const float* __restrict__ acc, const float* __restrict__ s,
    const float* __restrict__ b, float* __restrict__ out)
{
    int gid = blockIdx.x * 256 + threadIdx.x;
    if (gid >= N_NODES * F) return;
    int r = gid >> 6, c = gid & 63;
    float o = acc[gid] / (s[r] + 1e-16f) + b[c];
    out[gid] = fmaxf(o, 0.f);
}

extern "C" void kernel_launch(void* const* d_in, const int* in_sizes, int n_in,
                              void* d_out, int out_size, void* d_ws, size_t ws_size,
                              hipStream_t stream)
{
    const float* x   = (const float*)d_in[0];
    const int*   adj = (const int*)  d_in[1];
    const float* W1  = (const float*)d_in[2];
    const float* as1 = (const float*)d_in[3];
    const float* ad1 = (const float*)d_in[4];
    const float* b1  = (const float*)d_in[5];
    const float* bng = (const float*)d_in[6];
    const float* bnb = (const float*)d_in[7];
    const float* bnm = (const float*)d_in[8];
    const float* bnv = (const float*)d_in[9];
    const float* W2  = (const float*)d_in[10];
    const float* as2 = (const float*)d_in[11];
    const float* ad2 = (const float*)d_in[12];
    const float* b2  = (const float*)d_in[13];
    float* out = (float*)d_out;

    const int* esrc = adj;             // adj[0,:]
    const int* edst = adj + N_EDGES;   // adj[1,:]

    // workspace layout (floats)
    float*    ws    = (float*)d_ws;
    float*    hA    = ws;                          // N*64  (h1, then h2)
    float*    hB    = hA + (size_t)N_NODES * F;    // N*64  (acc L1, then gemm L2)
    float*    asrc  = hB + (size_t)N_NODES * F;    // N
    float*    adst  = asrc + N_NODES;              // N
    unsigned* m     = (unsigned*)(adst + N_NODES); // N
    float*    s     = (float*)(m + N_NODES);       // N
    float*    score = s + N_NODES;                 // EP

    dim3 blk(256);
    int nf_blocks   = (N_NODES * F) / 256;         // 25000 (exact)
    int edge_blocks = (EP + 255) / 256;
    int aggr_blocks = (EP * F) / 256;              // 425000 (exact)

    // ---------------- Layer 1 ----------------
    hipMemsetAsync(m,  0, N_NODES * 4, stream);            // enc(-inf) < 0..; every node has a self loop
    hipMemsetAsync(s,  0, N_NODES * 4, stream);
    hipMemsetAsync(hB, 0, (size_t)N_NODES * F * 4, stream);

    k_gemm      <<<nf_blocks,   blk, 0, stream>>>(x, W1, as1, ad1, hA, asrc, adst);
    k_edge_score<<<edge_blocks, blk, 0, stream>>>(esrc, edst, asrc, adst, score, m);
    k_edge_aggr <<<aggr_blocks, blk, 0, stream>>>(esrc, edst, score, m, hA, s, hB);
    // h2 = BN(relu(acc/s + b1)) -> overwrite hA (h1 no longer needed)
    k_finalize1 <<<nf_blocks,   blk, 0, stream>>>(hB, s, b1, bng, bnb, bnm, bnv, hA);

    // ---------------- Layer 2 ----------------
    hipMemsetAsync(m,   0, N_NODES * 4, stream);
    hipMemsetAsync(s,   0, N_NODES * 4, stream);
    hipMemsetAsync(out, 0, (size_t)N_NODES * F * 4, stream);  // use d_out as accumulator

    k_gemm      <<<nf_blocks,   blk, 0, stream>>>(hA, W2, as2, ad2, hB, asrc, adst);
    k_edge_score<<<edge_blocks, blk, 0, stream>>>(esrc, edst, asrc, adst, score, m);
    k_edge_aggr <<<aggr_blocks, blk, 0, stream>>>(esrc, edst, score, m, hB, s, out);
    k_finalize2 <<<nf_blocks,   blk, 0, stream>>>(out, s, b2, out);
}

// Round 4
// 694.542 us; speedup vs baseline: 2.0104x; 2.0104x over previous
//
#include <hip/hip_runtime.h>
#include <math.h>

#define N_NODES 100000
#define N_EDGES 1600000
#define EP (N_EDGES + N_NODES)   // edges + self loops = 1,700,000
#define F 64
#define NB 391                   // ceil(N_NODES / 256)

// ---- K1: h = X @ W ; asrc = h . aw_s ; adst = h . aw_d ----
// one wave per row; lane = column. Row broadcast via shfl instead of 64 scalar loads.
__global__ __launch_bounds__(256) void k_gemm(
    const float* __restrict__ X, const float* __restrict__ W,
    const float* __restrict__ aw_s, const float* __restrict__ aw_d,
    float* __restrict__ H, float* __restrict__ asrc, float* __restrict__ adst)
{
    int gid = blockIdx.x * 256 + threadIdx.x;
    int r = gid >> 6;
    int c = gid & 63;
    float xl = X[r * F + c];          // coalesced: wave holds the whole row
    float acc = 0.f;
#pragma unroll
    for (int k = 0; k < F; ++k)
        acc = fmaf(__shfl(xl, k, 64), W[k * F + c], acc);
    H[r * F + c] = acc;
    float va = acc * aw_s[c];
    float vd = acc * aw_d[c];
#pragma unroll
    for (int off = 32; off; off >>= 1) {
        va += __shfl_xor(va, off, 64);
        vd += __shfl_xor(vd, off, 64);
    }
    if (c == 0) { asrc[r] = va; adst[r] = vd; }
}

// ---- CSR build: histogram of dst ----
__global__ __launch_bounds__(256) void k_hist(
    const int* __restrict__ edst, int* __restrict__ deg)
{
    int e = blockIdx.x * 256 + threadIdx.x;
    if (e >= EP) return;
    int d_ = (e < N_EDGES) ? edst[e] : e - N_EDGES;   // self loops appended
    atomicAdd(deg + d_, 1);
}

// ---- CSR build: per-block partial sums ----
__global__ __launch_bounds__(256) void k_part(
    const int* __restrict__ deg, int* __restrict__ part)
{
    __shared__ int sm[256];
    int t = threadIdx.x;
    int i = blockIdx.x * 256 + t;
    sm[t] = (i < N_NODES) ? deg[i] : 0;
    __syncthreads();
    for (int off = 128; off; off >>= 1) {
        if (t < off) sm[t] += sm[t + off];
        __syncthreads();
    }
    if (t == 0) part[blockIdx.x] = sm[0];
}

// ---- CSR build: scan the 391 block sums (one block) ----
__global__ __launch_bounds__(512) void k_scanpart(
    const int* __restrict__ part, int* __restrict__ poff)
{
    __shared__ int sm[512];
    int t = threadIdx.x;
    int v = (t < NB) ? part[t] : 0;
    sm[t] = v;
    __syncthreads();
    for (int off = 1; off < 512; off <<= 1) {
        int x = (t >= off) ? sm[t - off] : 0;
        __syncthreads();
        sm[t] += x;
        __syncthreads();
    }
    if (t < NB) poff[t] = sm[t] - v;   // exclusive
}

// ---- CSR build: final exclusive scan; cursor overwrites deg in-place ----
__global__ __launch_bounds__(256) void k_scanfinal(
    int* __restrict__ deg, const int* __restrict__ poff, int* __restrict__ base)
{
    __shared__ int sm[256];
    int t = threadIdx.x;
    int i = blockIdx.x * 256 + t;
    int v = (i < N_NODES) ? deg[i] : 0;
    sm[t] = v;
    __syncthreads();
    for (int off = 1; off < 256; off <<= 1) {
        int x = (t >= off) ? sm[t - off] : 0;
        __syncthreads();
        sm[t] += x;
        __syncthreads();
    }
    if (i < N_NODES) {
        int ex = poff[blockIdx.x] + sm[t] - v;
        base[i] = ex;
        deg[i] = ex;            // becomes the scatter cursor
    }
    if (i == 0) base[N_NODES] = EP;
}

// ---- CSR build: scatter src ids into dst-grouped order ----
__global__ __launch_bounds__(256) void k_scatter(
    const int* __restrict__ esrc, const int* __restrict__ edst,
    int* __restrict__ cursor, int* __restrict__ ssrc)
{
    int e = blockIdx.x * 256 + threadIdx.x;
    if (e >= EP) return;
    int s_, d_;
    if (e < N_EDGES) { s_ = esrc[e]; d_ = edst[e]; }
    else             { s_ = d_ = e - N_EDGES; }
    int pos = atomicAdd(cursor + d_, 1);
    ssrc[pos] = s_;
}

// ---- K3: per-node softmax + aggregation + fused finalize. NO atomics. ----
// one wave per node; lane = feature. Scores computed on the fly.
template<bool BN>
__global__ __launch_bounds__(256) void k_aggr(
    const int* __restrict__ base, const int* __restrict__ ssrc,
    const float* __restrict__ asrc, const float* __restrict__ adst,
    const float* __restrict__ H, const float* __restrict__ bias,
    const float* __restrict__ gamma, const float* __restrict__ beta,
    const float* __restrict__ mean, const float* __restrict__ var,
    float* __restrict__ out)
{
    int w = threadIdx.x >> 6, lane = threadIdx.x & 63;
    int n = blockIdx.x * 4 + w;
    if (n >= N_NODES) return;
    int start = base[n], end = base[n + 1];
    float adn = adst[n];

    // phase A: segment max (lane-parallel over edges)
    float mx = -1e30f;
    for (int e = start + lane; e < end; e += 64) {
        float sc = asrc[ssrc[e]] + adn;
        sc = (sc >= 0.f) ? sc : 0.2f * sc;
        mx = fmaxf(mx, sc);
    }
#pragma unroll
    for (int off = 32; off; off >>= 1) mx = fmaxf(mx, __shfl_xor(mx, off, 64));

    // phase B: chunk of 64 edges -> lane-parallel weights, then serial
    // broadcast accumulate (coalesced 256B row gathers)
    float acc = 0.f, ssum = 0.f;
    for (int c = start; c < end; c += 64) {
        int e = c + lane;
        bool v_ = e < end;
        int s_ = v_ ? ssrc[e] : 0;
        float sc = asrc[s_] + adn;
        sc = (sc >= 0.f) ? sc : 0.2f * sc;
        float wg = v_ ? __expf(sc - mx) : 0.f;
        int cnt = min(64, end - c);
        for (int j = 0; j < cnt; ++j) {
            float wj = __shfl(wg, j, 64);
            int   sj = __shfl(s_, j, 64);
            acc = fmaf(wj, H[(size_t)sj * F + lane], acc);
            ssum += wj;
        }
    }
    float o = acc / (ssum + 1e-16f) + bias[lane];
    o = fmaxf(o, 0.f);
    if (BN)
        o = (o - mean[lane]) * rsqrtf(var[lane] + 1e-5f) * gamma[lane] + beta[lane];
    out[(size_t)n * F + lane] = o;
}

extern "C" void kernel_launch(void* const* d_in, const int* in_sizes, int n_in,
                              void* d_out, int out_size, void* d_ws, size_t ws_size,
                              hipStream_t stream)
{
    const float* x   = (const float*)d_in[0];
    const int*   adj = (const int*)  d_in[1];
    const float* W1  = (const float*)d_in[2];
    const float* as1 = (const float*)d_in[3];
    const float* ad1 = (const float*)d_in[4];
    const float* b1  = (const float*)d_in[5];
    const float* bng = (const float*)d_in[6];
    const float* bnb = (const float*)d_in[7];
    const float* bnm = (const float*)d_in[8];
    const float* bnv = (const float*)d_in[9];
    const float* W2  = (const float*)d_in[10];
    const float* as2 = (const float*)d_in[11];
    const float* ad2 = (const float*)d_in[12];
    const float* b2  = (const float*)d_in[13];
    float* out = (float*)d_out;

    const int* esrc = adj;
    const int* edst = adj + N_EDGES;

    // workspace layout
    float* ws   = (float*)d_ws;
    float* hA   = ws;                           // N*64: H1, then H2
    float* hB   = hA + (size_t)N_NODES * F;     // N*64: BN(relu(gat1)) = layer-2 input
    float* asrc = hB + (size_t)N_NODES * F;     // N
    float* adst = asrc + N_NODES;               // N
    int*   deg  = (int*)(adst + N_NODES);       // N (reused as scatter cursor)
    int*   base = deg + N_NODES;                // N+1
    int*   ssrc = base + (N_NODES + 1);         // EP (dst-grouped src ids)
    int*   part = ssrc + EP;                    // NB
    int*   poff = part + NB;                    // NB

    dim3 blk(256);
    int nf_blocks   = (N_NODES * F) / 256;      // 25000
    int edge_blocks = (EP + 255) / 256;         // 6641
    int node_blocks = (N_NODES + 3) / 4;        // 25000

    // ---- build CSR (dst-bucketed edges), reused by both layers ----
    hipMemsetAsync(deg, 0, N_NODES * 4, stream);
    k_hist     <<<edge_blocks, blk, 0, stream>>>(edst, deg);
    k_part     <<<NB,          blk, 0, stream>>>(deg, part);
    k_scanpart <<<1,           512, 0, stream>>>(part, poff);
    k_scanfinal<<<NB,          blk, 0, stream>>>(deg, poff, base);
    k_scatter  <<<edge_blocks, blk, 0, stream>>>(esrc, edst, deg, ssrc);

    // ---- Layer 1 ----
    k_gemm        <<<nf_blocks,   blk, 0, stream>>>(x, W1, as1, ad1, hA, asrc, adst);
    k_aggr<true>  <<<node_blocks, blk, 0, stream>>>(base, ssrc, asrc, adst, hA, b1,
                                                    bng, bnb, bnm, bnv, hB);
    // ---- Layer 2 ----
    k_gemm        <<<nf_blocks,   blk, 0, stream>>>(hB, W2, as2, ad2, hA, asrc, adst);
    k_aggr<false> <<<node_blocks, blk, 0, stream>>>(base, ssrc, asrc, adst, hA, b2,
                                                    nullptr, nullptr, nullptr, nullptr, out);
}

// Round 6
// 503.999 us; speedup vs baseline: 2.7705x; 1.3781x over previous
//
#include <hip/hip_runtime.h>
#include <math.h>

#define N_NODES 100000
#define N_EDGES 1600000
#define EP (N_EDGES + N_NODES)   // edges + self loops = 1,700,000
#define F 64
#define NB 391                   // ceil(N_NODES / 256)

// ---- K1: h = X @ W ; asrc = h . aw_s ; adst = h . aw_d ----
__global__ __launch_bounds__(256) void k_gemm(
    const float* __restrict__ X, const float* __restrict__ W,
    const float* __restrict__ aw_s, const float* __restrict__ aw_d,
    float* __restrict__ H, float* __restrict__ asrc, float* __restrict__ adst)
{
    int gid = blockIdx.x * 256 + threadIdx.x;
    int r = gid >> 6;
    int c = gid & 63;
    float xl = X[r * F + c];          // coalesced: wave holds the whole row
    float acc = 0.f;
#pragma unroll
    for (int k = 0; k < F; ++k)
        acc = fmaf(__shfl(xl, k, 64), W[k * F + c], acc);
    H[r * F + c] = acc;
    float va = acc * aw_s[c];
    float vd = acc * aw_d[c];
#pragma unroll
    for (int off = 32; off; off >>= 1) {
        va += __shfl_xor(va, off, 64);
        vd += __shfl_xor(vd, off, 64);
    }
    if (c == 0) { asrc[r] = va; adst[r] = vd; }
}

// ---- CSR build: histogram of dst + per-edge rank (fused; rank write coalesced) ----
__global__ __launch_bounds__(256) void k_hist(
    const int* __restrict__ edst, int* __restrict__ deg, int* __restrict__ rank)
{
    int e = blockIdx.x * 256 + threadIdx.x;
    if (e >= EP) return;
    int d_ = (e < N_EDGES) ? edst[e] : e - N_EDGES;   // self loops appended
    rank[e] = atomicAdd(deg + d_, 1);
}

// ---- CSR build: per-block partial sums ----
__global__ __launch_bounds__(256) void k_part(
    const int* __restrict__ deg, int* __restrict__ part)
{
    __shared__ int sm[256];
    int t = threadIdx.x;
    int i = blockIdx.x * 256 + t;
    sm[t] = (i < N_NODES) ? deg[i] : 0;
    __syncthreads();
    for (int off = 128; off; off >>= 1) {
        if (t < off) sm[t] += sm[t + off];
        __syncthreads();
    }
    if (t == 0) part[blockIdx.x] = sm[0];
}

// ---- CSR build: scan the 391 block sums (one block) ----
__global__ __launch_bounds__(512) void k_scanpart(
    const int* __restrict__ part, int* __restrict__ poff)
{
    __shared__ int sm[512];
    int t = threadIdx.x;
    int v = (t < NB) ? part[t] : 0;
    sm[t] = v;
    __syncthreads();
    for (int off = 1; off < 512; off <<= 1) {
        int x = (t >= off) ? sm[t - off] : 0;
        __syncthreads();
        sm[t] += x;
        __syncthreads();
    }
    if (t < NB) poff[t] = sm[t] - v;   // exclusive
}

// ---- CSR build: final exclusive scan -> base offsets ----
__global__ __launch_bounds__(256) void k_scanfinal(
    const int* __restrict__ deg, const int* __restrict__ poff, int* __restrict__ base)
{
    __shared__ int sm[256];
    int t = threadIdx.x;
    int i = blockIdx.x * 256 + t;
    int v = (i < N_NODES) ? deg[i] : 0;
    sm[t] = v;
    __syncthreads();
    for (int off = 1; off < 256; off <<= 1) {
        int x = (t >= off) ? sm[t - off] : 0;
        __syncthreads();
        sm[t] += x;
        __syncthreads();
    }
    if (i < N_NODES) base[i] = poff[blockIdx.x] + sm[t] - v;
    if (i == 0) base[N_NODES] = EP;
}

// ---- CSR build: scatter src ids into dst-grouped order (no atomics) ----
__global__ __launch_bounds__(256) void k_scatter(
    const int* __restrict__ esrc, const int* __restrict__ edst,
    const int* __restrict__ base, const int* __restrict__ rank,
    int* __restrict__ ssrc)
{
    int e = blockIdx.x * 256 + threadIdx.x;
    if (e >= EP) return;
    int s_, d_;
    if (e < N_EDGES) { s_ = esrc[e]; d_ = edst[e]; }
    else             { s_ = d_ = e - N_EDGES; }
    ssrc[base[d_] + rank[e]] = s_;
}

// ---- K3: per-node softmax + aggregation + fused finalize. NO atomics. ----
// one wave per node. 4 edges processed concurrently: lane = (group, quad),
// each lane float4-loads 16B of one of 4 H-rows -> 4 row-gathers in flight.
template<bool BN>
__global__ __launch_bounds__(256) void k_aggr(
    const int* __restrict__ base, const int* __restrict__ ssrc,
    const float* __restrict__ asrc, const float* __restrict__ adst,
    const float* __restrict__ H, const float* __restrict__ bias,
    const float* __restrict__ gamma, const float* __restrict__ beta,
    const float* __restrict__ mean, const float* __restrict__ var,
    float* __restrict__ out)
{
    int w = threadIdx.x >> 6, lane = threadIdx.x & 63;
    int n = blockIdx.x * 4 + w;
    if (n >= N_NODES) return;
    int start = base[n], end = base[n + 1];
    float adn = adst[n];

    // phase A: segment max (lane-parallel over edges)
    float mx = -1e30f;
    for (int e = start + lane; e < end; e += 64) {
        float sc = asrc[ssrc[e]] + adn;
        sc = (sc >= 0.f) ? sc : 0.2f * sc;
        mx = fmaxf(mx, sc);
    }
#pragma unroll
    for (int off = 32; off; off >>= 1) mx = fmaxf(mx, __shfl_xor(mx, off, 64));

    // phase B: chunks of 64 edges; weights lane-parallel, then 4-edges-at-a-time
    // broadcast accumulate. Invalid lanes have wg=0, s_=0 -> contribute nothing.
    int g = lane >> 4, q = lane & 15;
    float4 acc = {0.f, 0.f, 0.f, 0.f};
    float ssum = 0.f;
    for (int c = start; c < end; c += 64) {
        int e = c + lane;
        bool v_ = e < end;
        int s_ = v_ ? ssrc[e] : 0;
        float sc = asrc[s_] + adn;
        sc = (sc >= 0.f) ? sc : 0.2f * sc;
        float wg = v_ ? __expf(sc - mx) : 0.f;
        ssum += wg;
        int cnt = min(64, end - c);
        for (int j = 0; j < cnt; j += 4) {
            float wj = __shfl(wg, j + g, 64);
            int   sj = __shfl(s_, j + g, 64);
            const float4 hv = *(const float4*)(H + (size_t)sj * F + q * 4);
            acc.x = fmaf(wj, hv.x, acc.x);
            acc.y = fmaf(wj, hv.y, acc.y);
            acc.z = fmaf(wj, hv.z, acc.z);
            acc.w = fmaf(wj, hv.w, acc.w);
        }
    }
    // reduce acc across the 4 groups; ssum across all 64 lanes
#pragma unroll
    for (int off = 16; off <= 32; off <<= 1) {
        acc.x += __shfl_xor(acc.x, off, 64);
        acc.y += __shfl_xor(acc.y, off, 64);
        acc.z += __shfl_xor(acc.z, off, 64);
        acc.w += __shfl_xor(acc.w, off, 64);
    }
#pragma unroll
    for (int off = 32; off; off >>= 1) ssum += __shfl_xor(ssum, off, 64);

    if (g == 0) {   // 16 lanes store one float4 each -> coalesced 256B row
        float inv = 1.f / (ssum + 1e-16f);
        const float4 bb = ((const float4*)bias)[q];
        float4 o;
        o.x = fmaxf(fmaf(acc.x, inv, bb.x), 0.f);
        o.y = fmaxf(fmaf(acc.y, inv, bb.y), 0.f);
        o.z = fmaxf(fmaf(acc.z, inv, bb.z), 0.f);
        o.w = fmaxf(fmaf(acc.w, inv, bb.w), 0.f);
        if (BN) {
            const float4 gm = ((const float4*)gamma)[q];
            const float4 bt = ((const float4*)beta)[q];
            const float4 mn = ((const float4*)mean)[q];
            const float4 vr = ((const float4*)var)[q];
            o.x = (o.x - mn.x) * rsqrtf(vr.x + 1e-5f) * gm.x + bt.x;
            o.y = (o.y - mn.y) * rsqrtf(vr.y + 1e-5f) * gm.y + bt.y;
            o.z = (o.z - mn.z) * rsqrtf(vr.z + 1e-5f) * gm.z + bt.z;
            o.w = (o.w - mn.w) * rsqrtf(vr.w + 1e-5f) * gm.w + bt.w;
        }
        ((float4*)(out + (size_t)n * F))[q] = o;
    }
}

extern "C" void kernel_launch(void* const* d_in, const int* in_sizes, int n_in,
                              void* d_out, int out_size, void* d_ws, size_t ws_size,
                              hipStream_t stream)
{
    const float* x   = (const float*)d_in[0];
    const int*   adj = (const int*)  d_in[1];
    const float* W1  = (const float*)d_in[2];
    const float* as1 = (const float*)d_in[3];
    const float* ad1 = (const float*)d_in[4];
    const float* b1  = (const float*)d_in[5];
    const float* bng = (const float*)d_in[6];
    const float* bnb = (const float*)d_in[7];
    const float* bnm = (const float*)d_in[8];
    const float* bnv = (const float*)d_in[9];
    const float* W2  = (const float*)d_in[10];
    const float* as2 = (const float*)d_in[11];
    const float* ad2 = (const float*)d_in[12];
    const float* b2  = (const float*)d_in[13];
    float* out = (float*)d_out;

    const int* esrc = adj;
    const int* edst = adj + N_EDGES;

    // workspace layout
    float* ws   = (float*)d_ws;
    float* hA   = ws;                           // N*64: rank (CSR phase), then H1/H2
    float* hB   = hA + (size_t)N_NODES * F;     // N*64: BN(relu(gat1)) = layer-2 input
    float* asrc = hB + (size_t)N_NODES * F;     // N
    float* adst = asrc + N_NODES;               // N
    int*   deg  = (int*)(adst + N_NODES);       // N
    int*   base = deg + N_NODES;                // N+1
    int*   ssrc = base + (N_NODES + 1);         // EP (dst-grouped src ids)
    int*   part = ssrc + EP;                    // NB
    int*   poff = part + NB;                    // NB
    int*   rank = (int*)hA;                     // EP ints, dead before k_gemm writes hA

    dim3 blk(256);
    int nf_blocks   = (N_NODES * F) / 256;      // 25000
    int edge_blocks = (EP + 255) / 256;         // 6641
    int node_blocks = (N_NODES + 3) / 4;        // 25000

    // ---- build CSR (dst-bucketed edges), reused by both layers ----
    hipMemsetAsync(deg, 0, N_NODES * 4, stream);
    k_hist     <<<edge_blocks, blk, 0, stream>>>(edst, deg, rank);
    k_part     <<<NB,          blk, 0, stream>>>(deg, part);
    k_scanpart <<<1,           512, 0, stream>>>(part, poff);
    k_scanfinal<<<NB,          blk, 0, stream>>>(deg, poff, base);
    k_scatter  <<<edge_blocks, blk, 0, stream>>>(esrc, edst, base, rank, ssrc);

    // ---- Layer 1 ----
    k_gemm        <<<nf_blocks,   blk, 0, stream>>>(x, W1, as1, ad1, hA, asrc, adst);
    k_aggr<true>  <<<node_blocks, blk, 0, stream>>>(base, ssrc, asrc, adst, hA, b1,
                                                    bng, bnb, bnm, bnv, hB);
    // ---- Layer 2 ----
    k_gemm        <<<nf_blocks,   blk, 0, stream>>>(hB, W2, as2, ad2, hA, asrc, adst);
    k_aggr<false> <<<node_blocks, blk, 0, stream>>>(base, ssrc, asrc, adst, hA, b2,
                                                    nullptr, nullptr, nullptr, nullptr, out);
}